// Round 1
// baseline (503.235 us; speedup 1.0000x reference)
//
#include <hip/hip_runtime.h>
#include <hip/hip_bf16.h>
#include <float.h>

// Problem constants (from setup_inputs): B=16, N=21504, C=80, G=64, K=9
#define BB 16
#define NN 21504
#define CC 80
#define GG 64
#define KK 9
#define ALPHA 0.25f
// GAMMA = 2.0 -> (1-p_t)^2

// ---------------- focal helpers ----------------
// f0(x): focal value when t=0 = 0.75 * softplus(x) * sigmoid(x)^2
__device__ __forceinline__ float focal_t0(float x) {
    float ax = fabsf(x);
    float em = __expf(-ax);              // e^{-|x|} in (0,1]
    float sp = __logf(1.0f + em);        // log(1+e^{-|x|})
    float spx = fmaxf(x, 0.0f) + sp;     // softplus(x)
    float r = 1.0f / (1.0f + em);
    float p = (x >= 0.0f) ? r : em * r;  // sigmoid(x)
    return 0.75f * spx * p * p;
}

// f1(x) - f0(x): correction for a position where t=1
__device__ __forceinline__ float focal_corr(float x) {
    float ax = fabsf(x);
    float em = __expf(-ax);
    float sp = __logf(1.0f + em);
    float spx = fmaxf(x, 0.0f) + sp;     // softplus(x)
    float spn = fmaxf(-x, 0.0f) + sp;    // softplus(-x)
    float r = 1.0f / (1.0f + em);
    float p = (x >= 0.0f) ? r : em * r;  // sigmoid(x)
    float q = 1.0f - p;                  // sigmoid(-x)
    float f1 = 0.25f * spn * q * q;
    float f0 = 0.75f * spx * p * p;
    return f1 - f0;
}

// ---------------- top-9 helpers ----------------
__device__ __forceinline__ bool lessdi(float d1, int i1, float d2, int i2) {
    return (d1 < d2) || (d1 == d2 && i1 < i2);
}

__device__ __forceinline__ void ins9(float kd[KK], int ki[KK], float d, int i) {
    if (!lessdi(d, i, kd[KK - 1], ki[KK - 1])) return;
    kd[KK - 1] = d; ki[KK - 1] = i;
#pragma unroll
    for (int j = KK - 1; j > 0; --j) {
        bool sw = lessdi(kd[j], ki[j], kd[j - 1], ki[j - 1]);
        if (sw) {
            float td = kd[j]; kd[j] = kd[j - 1]; kd[j - 1] = td;
            int ti = ki[j]; ki[j] = ki[j - 1]; ki[j - 1] = ti;
        }
    }
}

// Kernel A: one wave per (b,g). Top-9 nearest locations, then bbox L1 + GIoU
// for the 9 selected predictions; writes selected indices to `sel`.
__global__ __launch_bounds__(256) void topk_bbox_kernel(
    const float* __restrict__ locations,   // (N,2)
    const float* __restrict__ pred_boxes,  // (B,N,4)
    const float* __restrict__ gt_boxes,    // (B,G,4)
    double* __restrict__ acc,              // [0]=cls, [1]=bbox, [2]=giou
    int* __restrict__ sel)                 // (B*G*K)
{
    int wave = (blockIdx.x * blockDim.x + threadIdx.x) >> 6;
    int lane = threadIdx.x & 63;
    if (wave >= BB * GG) return;
    int b = wave >> 6;
    int g = wave & (GG - 1);

    const float4 gt = ((const float4*)gt_boxes)[b * GG + g];
    float cx = gt.x, cy = gt.y;

    float kd[KK];
    int ki[KK];
#pragma unroll
    for (int j = 0; j < KK; ++j) { kd[j] = FLT_MAX; ki[j] = 0x7fffffff; }

    const float2* loc = (const float2*)locations;
    for (int n = lane; n < NN; n += 64) {
        float2 L = loc[n];
        float dx = cx - L.x, dy = cy - L.y;
        float d2 = dx * dx + dy * dy;
        ins9(kd, ki, d2, n);
    }

    // butterfly merge across the wave
    for (int s = 1; s < 64; s <<= 1) {
        float pd[KK]; int pi[KK];
#pragma unroll
        for (int j = 0; j < KK; ++j) {
            pd[j] = __shfl_xor(kd[j], s);
            pi[j] = __shfl_xor(ki[j], s);
        }
#pragma unroll
        for (int j = 0; j < KK; ++j) ins9(kd, ki, pd[j], pi[j]);
    }

    if (lane == 0) {
#pragma unroll
        for (int j = 0; j < KK; ++j) sel[wave * KK + j] = ki[j];
    }

    // lanes 0..8 each take one selected index (all lanes hold identical lists)
    int n = 0;
#pragma unroll
    for (int j = 0; j < KK; ++j) if (lane == j) n = ki[j];

    float l1 = 0.0f, gio = 0.0f;
    if (lane < KK) {
        float4 p = ((const float4*)pred_boxes)[b * NN + n];
        l1 = fabsf(p.x - gt.x) + fabsf(p.y - gt.y) + fabsf(p.z - gt.z) + fabsf(p.w - gt.w);

        // cxcywh -> xyxy
        float ax1 = p.x - 0.5f * p.z, ay1 = p.y - 0.5f * p.w;
        float ax2 = p.x + 0.5f * p.z, ay2 = p.y + 0.5f * p.w;
        float bx1 = gt.x - 0.5f * gt.z, by1 = gt.y - 0.5f * gt.w;
        float bx2 = gt.x + 0.5f * gt.z, by2 = gt.y + 0.5f * gt.w;

        float area_a = (ax2 - ax1) * (ay2 - ay1);
        float area_b = (bx2 - bx1) * (by2 - by1);
        float ix1 = fmaxf(ax1, bx1), iy1 = fmaxf(ay1, by1);
        float ix2 = fminf(ax2, bx2), iy2 = fminf(ay2, by2);
        float iw = fmaxf(ix2 - ix1, 0.0f), ih = fmaxf(iy2 - iy1, 0.0f);
        float inter = iw * ih;
        float uni = area_a + area_b - inter;
        float iou = inter / uni;
        float ccx1 = fminf(ax1, bx1), ccy1 = fminf(ay1, by1);
        float ccx2 = fmaxf(ax2, bx2), ccy2 = fmaxf(ay2, by2);
        float cw = fmaxf(ccx2 - ccx1, 0.0f), ch = fmaxf(ccy2 - ccy1, 0.0f);
        float ac = cw * ch;
        float giou = iou - (ac - uni) / ac;
        gio = 1.0f - giou;
    }

    // wave reduce (lanes >= 9 contribute 0)
#pragma unroll
    for (int o = 32; o > 0; o >>= 1) {
        l1 += __shfl_down(l1, o);
        gio += __shfl_down(gio, o);
    }
    if (lane == 0) {
        atomicAdd(&acc[1], (double)l1);
        atomicAdd(&acc[2], (double)gio);
    }
}

// Kernel B: main focal sum over all B*N*C logits (t=0 formula everywhere)
__global__ __launch_bounds__(256) void focal_main_kernel(
    const float* __restrict__ logits, double* __restrict__ acc, int nvec4)
{
    const float4* v = (const float4*)logits;
    float s0 = 0.f, s1 = 0.f, s2 = 0.f, s3 = 0.f;
    int stride = gridDim.x * blockDim.x;
    for (int i = blockIdx.x * blockDim.x + threadIdx.x; i < nvec4; i += stride) {
        float4 x = v[i];
        s0 += focal_t0(x.x);
        s1 += focal_t0(x.y);
        s2 += focal_t0(x.z);
        s3 += focal_t0(x.w);
    }
    double d = (double)((s0 + s1) + (s2 + s3));
#pragma unroll
    for (int o = 32; o > 0; o >>= 1) d += __shfl_down(d, o);
    __shared__ double wsum[4];
    if ((threadIdx.x & 63) == 0) wsum[threadIdx.x >> 6] = d;
    __syncthreads();
    if (threadIdx.x == 0) {
        atomicAdd(&acc[0], wsum[0] + wsum[1] + wsum[2] + wsum[3]);
    }
}

// Kernel C: per-image dedup of the 576 selected (n, class) keys, apply
// focal correction f1-f0 once per unique key.
__global__ __launch_bounds__(256) void correction_kernel(
    const float* __restrict__ logits, const int* __restrict__ sel,
    const int* __restrict__ gt_labels, double* __restrict__ acc)
{
    int b = blockIdx.x;
    __shared__ int keys[GG * KK];
    for (int e = threadIdx.x; e < GG * KK; e += blockDim.x) {
        int g = e / KK;
        int n = sel[(b * GG + g) * KK + (e - g * KK)];
        keys[e] = n * CC + gt_labels[b * GG + g];
    }
    __syncthreads();

    float corr = 0.0f;
    for (int e = threadIdx.x; e < GG * KK; e += blockDim.x) {
        int k = keys[e];
        bool uniq = true;
        for (int e2 = 0; e2 < e; ++e2) {
            if (keys[e2] == k) { uniq = false; break; }
        }
        if (uniq) {
            float x = logits[b * NN * CC + k];
            corr += focal_corr(x);
        }
    }
    double d = (double)corr;
#pragma unroll
    for (int o = 32; o > 0; o >>= 1) d += __shfl_down(d, o);
    __shared__ double wsum[4];
    if ((threadIdx.x & 63) == 0) wsum[threadIdx.x >> 6] = d;
    __syncthreads();
    if (threadIdx.x == 0) {
        atomicAdd(&acc[0], wsum[0] + wsum[1] + wsum[2] + wsum[3]);
    }
}

// Kernel D: finalize means
__global__ void finalize_kernel(const double* __restrict__ acc, float* __restrict__ out)
{
    if (threadIdx.x == 0 && blockIdx.x == 0) {
        out[0] = (float)(acc[0] / (double)((long long)BB * NN * CC));
        out[1] = (float)(acc[1] / (double)(BB * GG * KK * 4));
        out[2] = (float)(acc[2] / (double)(BB * GG * KK));
    }
}

extern "C" void kernel_launch(void* const* d_in, const int* in_sizes, int n_in,
                              void* d_out, int out_size, void* d_ws, size_t ws_size,
                              hipStream_t stream) {
    const float* pred_logits = (const float*)d_in[0];  // (B,N,C)
    const float* pred_boxes  = (const float*)d_in[1];  // (B,N,4)
    const float* locations   = (const float*)d_in[2];  // (N,2)
    const float* gt_boxes    = (const float*)d_in[3];  // (B,G,4)
    const int*   gt_labels   = (const int*)d_in[4];    // (B,G)
    float* out = (float*)d_out;

    double* acc = (double*)d_ws;                  // 3 doubles at offset 0
    int* sel = (int*)((char*)d_ws + 64);          // B*G*K ints

    hipMemsetAsync(d_ws, 0, 64, stream);

    // A: 1024 waves -> 256 blocks x 256 threads
    topk_bbox_kernel<<<256, 256, 0, stream>>>(locations, pred_boxes, gt_boxes, acc, sel);

    // B: focal main sum
    int nvec4 = (BB * NN * CC) / 4;
    focal_main_kernel<<<2048, 256, 0, stream>>>(pred_logits, acc, nvec4);

    // C: corrections (one block per image)
    correction_kernel<<<BB, 256, 0, stream>>>(pred_logits, sel, gt_labels, acc);

    // D: finalize
    finalize_kernel<<<1, 64, 0, stream>>>(acc, out);
}

// Round 5
// 432.256 us; speedup vs baseline: 1.1642x; 1.1642x over previous
//
#include <hip/hip_runtime.h>
#include <hip/hip_bf16.h>
#include <float.h>

// Problem constants (from setup_inputs): B=16, N=21504, C=80, G=64, K=9
#define BB 16
#define NN 21504
#define CC 80
#define GG 64
#define KK 9
#define PER_LANE (NN / 64)   // 336 elements per lane (one wave scans all N)

// ---------------- focal helpers ----------------
// f0(x): focal value when t=0 = 0.75 * softplus(x) * sigmoid(x)^2
__device__ __forceinline__ float focal_t0(float x) {
    float ax = fabsf(x);
    float em = __expf(-ax);              // e^{-|x|} in (0,1]
    float sp = __logf(1.0f + em);        // log(1+e^{-|x|})
    float spx = fmaxf(x, 0.0f) + sp;     // softplus(x)
    float r = 1.0f / (1.0f + em);
    float p = (x >= 0.0f) ? r : em * r;  // sigmoid(x)
    return 0.75f * spx * p * p;
}

// f1(x) - f0(x): correction for a position where t=1
__device__ __forceinline__ float focal_corr(float x) {
    float ax = fabsf(x);
    float em = __expf(-ax);
    float sp = __logf(1.0f + em);
    float spx = fmaxf(x, 0.0f) + sp;     // softplus(x)
    float spn = fmaxf(-x, 0.0f) + sp;    // softplus(-x)
    float r = 1.0f / (1.0f + em);
    float p = (x >= 0.0f) ? r : em * r;  // sigmoid(x)
    float q = 1.0f - p;                  // sigmoid(-x)
    float f1 = 0.25f * spn * q * q;
    float f0 = 0.75f * spx * p * p;
    return f1 - f0;
}

// shared between both scan passes so values are bit-identical
__device__ __forceinline__ float dist2(float cx, float cy, float2 L) {
    float dx = cx - L.x, dy = cy - L.y;
    return dx * dx + dy * dy;
}

// Kernel A: ONE WAVE per (b,g); 4 independent waves per block.
// Registers + shuffles ONLY (no LDS, no barriers, no ballot, no atomics
// until the two final global double atomicAdds, same as the R1 kernel).
//   1. per-lane min d^2 over 336 strided elements
//   2. T = 9th-smallest lane-min via 9 masked butterfly-min rounds
//      (guarantees >= 9 distinct elements have d2 <= T)
//   3. rescan; each lane keeps up to 6 (d2,n) candidates in named scalars
//   4. if any lane overflowed (shuffle-max flag; ~never): exact fallback of
//      9 lex-min rescans. Else: 9 butterfly lex-min extraction rounds.
//   5. bbox L1 + GIoU on lanes 0..8, wave-reduce, global atomicAdd.
__global__ __launch_bounds__(256) void topk_bbox_kernel(
    const float* __restrict__ locations,   // (N,2)
    const float* __restrict__ pred_boxes,  // (B,N,4)
    const float* __restrict__ gt_boxes,    // (B,G,4)
    double* __restrict__ acc,              // [0]=cls, [1]=bbox, [2]=giou
    int* __restrict__ sel)                 // (B*G*K)
{
    int wv   = threadIdx.x >> 6;
    int lane = threadIdx.x & 63;
    int pair = blockIdx.x * 4 + wv;        // 0..1023
    int b = pair >> 6;
    int g = pair & (GG - 1);

    const float4 gt = ((const float4*)gt_boxes)[b * GG + g];
    float cx = gt.x, cy = gt.y;
    const float2* loc = (const float2*)locations;

    // Phase 1: per-lane min over 336 strided elements
    float md = FLT_MAX;
#pragma unroll 8
    for (int t = 0; t < PER_LANE; ++t) {
        md = fminf(md, dist2(cx, cy, loc[lane + t * 64]));
    }

    // Phase 2: T = 9th-smallest lane minimum. Masked-min rounds; ties can
    // only enlarge T, which keeps the candidate set a superset of the top-9.
    float v = md;
    float T = FLT_MAX;
    for (int r = 0; r < KK; ++r) {
        float m = v;
        for (int s = 1; s < 64; s <<= 1) m = fminf(m, __shfl_xor(m, s));
        T = m;
        if (v == m) v = FLT_MAX;
    }

    // Phase 3: rescan, collect up to 6 candidates per lane in named scalars
    float sd0 = FLT_MAX, sd1 = FLT_MAX, sd2 = FLT_MAX,
          sd3 = FLT_MAX, sd4 = FLT_MAX, sd5 = FLT_MAX;
    int   sn0 = 0x7fffffff, sn1 = 0x7fffffff, sn2 = 0x7fffffff,
          sn3 = 0x7fffffff, sn4 = 0x7fffffff, sn5 = 0x7fffffff;
    int cnt = 0;
#pragma unroll 4
    for (int t = 0; t < PER_LANE; ++t) {
        int n = lane + t * 64;
        float d2 = dist2(cx, cy, loc[n]);
        if (d2 <= T) {
            if (cnt == 0)      { sd0 = d2; sn0 = n; }
            else if (cnt == 1) { sd1 = d2; sn1 = n; }
            else if (cnt == 2) { sd2 = d2; sn2 = n; }
            else if (cnt == 3) { sd3 = d2; sn3 = n; }
            else if (cnt == 4) { sd4 = d2; sn4 = n; }
            else if (cnt == 5) { sd5 = d2; sn5 = n; }
            ++cnt;
        }
    }
    int ovf = (cnt > 6) ? 1 : 0;
    for (int s = 1; s < 64; s <<= 1) ovf = max(ovf, __shfl_xor(ovf, s));

    int myn = 0;
    if (ovf == 0) {
        // Phase 4a: 9 butterfly lex-min extraction rounds over the slots
        for (int r = 0; r < KK; ++r) {
            float bv = sd0; int bn = sn0;
            bool c;
            c = sd1 < bv; bv = c ? sd1 : bv; bn = c ? sn1 : bn;
            c = sd2 < bv; bv = c ? sd2 : bv; bn = c ? sn2 : bn;
            c = sd3 < bv; bv = c ? sd3 : bv; bn = c ? sn3 : bn;
            c = sd4 < bv; bv = c ? sd4 : bv; bn = c ? sn4 : bn;
            c = sd5 < bv; bv = c ? sd5 : bv; bn = c ? sn5 : bn;
            for (int s = 1; s < 64; s <<= 1) {
                float ov = __shfl_xor(bv, s);
                int   on = __shfl_xor(bn, s);
                bool cc = (ov < bv) || (ov == bv && on < bn);
                bv = cc ? ov : bv;
                bn = cc ? on : bn;
            }
            // clear extracted (n unique per slot)
            if (sn0 == bn) sd0 = FLT_MAX;
            if (sn1 == bn) sd1 = FLT_MAX;
            if (sn2 == bn) sd2 = FLT_MAX;
            if (sn3 == bn) sd3 = FLT_MAX;
            if (sn4 == bn) sd4 = FLT_MAX;
            if (sn5 == bn) sd5 = FLT_MAX;
            if (lane == r) myn = bn;
            if (lane == 0) sel[pair * KK + r] = bn;
        }
    } else {
        // Phase 4b (rare exact fallback): 9 rounds of lex-min rescan
        float lastD = -1.0f; int lastN = -1;
        for (int r = 0; r < KK; ++r) {
            float bv = FLT_MAX; int bn = 0x7fffffff;
            for (int t = 0; t < PER_LANE; ++t) {
                int n = lane + t * 64;
                float d2 = dist2(cx, cy, loc[n]);
                bool gtr = (d2 > lastD) || (d2 == lastD && n > lastN);
                bool cc = gtr && ((d2 < bv) || (d2 == bv && n < bn));
                bv = cc ? d2 : bv;
                bn = cc ? n : bn;
            }
            for (int s = 1; s < 64; s <<= 1) {
                float ov = __shfl_xor(bv, s);
                int   on = __shfl_xor(bn, s);
                bool cc = (ov < bv) || (ov == bv && on < bn);
                bv = cc ? ov : bv;
                bn = cc ? on : bn;
            }
            lastD = bv; lastN = bn;
            if (lane == r) myn = bn;
            if (lane == 0) sel[pair * KK + r] = bn;
        }
    }
    myn = myn < 0 ? 0 : (myn >= NN ? NN - 1 : myn);  // fault guard

    // Phase 5: bbox L1 + GIoU for the 9 selected (lanes 0..8)
    float l1 = 0.0f, gio = 0.0f;
    if (lane < KK) {
        float4 p = ((const float4*)pred_boxes)[b * NN + myn];
        l1 = fabsf(p.x - gt.x) + fabsf(p.y - gt.y) + fabsf(p.z - gt.z) + fabsf(p.w - gt.w);

        float ax1 = p.x - 0.5f * p.z, ay1 = p.y - 0.5f * p.w;
        float ax2 = p.x + 0.5f * p.z, ay2 = p.y + 0.5f * p.w;
        float bx1 = gt.x - 0.5f * gt.z, by1 = gt.y - 0.5f * gt.w;
        float bx2 = gt.x + 0.5f * gt.z, by2 = gt.y + 0.5f * gt.w;

        float area_a = (ax2 - ax1) * (ay2 - ay1);
        float area_b = (bx2 - bx1) * (by2 - by1);
        float ix1 = fmaxf(ax1, bx1), iy1 = fmaxf(ay1, by1);
        float ix2 = fminf(ax2, bx2), iy2 = fminf(ay2, by2);
        float iw = fmaxf(ix2 - ix1, 0.0f), ih = fmaxf(iy2 - iy1, 0.0f);
        float inter = iw * ih;
        float uni = area_a + area_b - inter;
        float iou = inter / uni;
        float ccx1 = fminf(ax1, bx1), ccy1 = fminf(ay1, by1);
        float ccx2 = fmaxf(ax2, bx2), ccy2 = fmaxf(ay2, by2);
        float cw = fmaxf(ccx2 - ccx1, 0.0f), ch = fmaxf(ccy2 - ccy1, 0.0f);
        float ac = cw * ch;
        float giou = iou - (ac - uni) / ac;
        gio = 1.0f - giou;
    }
    for (int o = 32; o > 0; o >>= 1) {
        l1 += __shfl_down(l1, o);
        gio += __shfl_down(gio, o);
    }
    if (lane == 0) {
        atomicAdd(&acc[1], (double)l1);
        atomicAdd(&acc[2], (double)gio);
    }
}

// Kernel B: main focal sum over all B*N*C logits (t=0 formula everywhere)
__global__ __launch_bounds__(256) void focal_main_kernel(
    const float* __restrict__ logits, double* __restrict__ acc, int nvec4)
{
    const float4* v = (const float4*)logits;
    float s0 = 0.f, s1 = 0.f, s2 = 0.f, s3 = 0.f;
    int stride = gridDim.x * blockDim.x;
    for (int i = blockIdx.x * blockDim.x + threadIdx.x; i < nvec4; i += stride) {
        float4 x = v[i];
        s0 += focal_t0(x.x);
        s1 += focal_t0(x.y);
        s2 += focal_t0(x.z);
        s3 += focal_t0(x.w);
    }
    double d = (double)((s0 + s1) + (s2 + s3));
#pragma unroll
    for (int o = 32; o > 0; o >>= 1) d += __shfl_down(d, o);
    __shared__ double wsum[4];
    if ((threadIdx.x & 63) == 0) wsum[threadIdx.x >> 6] = d;
    __syncthreads();
    if (threadIdx.x == 0) {
        atomicAdd(&acc[0], wsum[0] + wsum[1] + wsum[2] + wsum[3]);
    }
}

// Kernel C: per-image dedup of the 576 selected (n, class) keys, apply
// focal correction f1-f0 once per unique key.
__global__ __launch_bounds__(256) void correction_kernel(
    const float* __restrict__ logits, const int* __restrict__ sel,
    const int* __restrict__ gt_labels, double* __restrict__ acc)
{
    int b = blockIdx.x;
    __shared__ int keys[GG * KK];
    for (int e = threadIdx.x; e < GG * KK; e += blockDim.x) {
        int g = e / KK;
        int n = sel[(b * GG + g) * KK + (e - g * KK)];
        keys[e] = n * CC + gt_labels[b * GG + g];
    }
    __syncthreads();

    float corr = 0.0f;
    for (int e = threadIdx.x; e < GG * KK; e += blockDim.x) {
        int k = keys[e];
        bool uniq = true;
        for (int e2 = 0; e2 < e; ++e2) {
            if (keys[e2] == k) { uniq = false; break; }
        }
        if (uniq) {
            float x = logits[b * NN * CC + k];
            corr += focal_corr(x);
        }
    }
    double d = (double)corr;
#pragma unroll
    for (int o = 32; o > 0; o >>= 1) d += __shfl_down(d, o);
    __shared__ double wsum[4];
    if ((threadIdx.x & 63) == 0) wsum[threadIdx.x >> 6] = d;
    __syncthreads();
    if (threadIdx.x == 0) {
        atomicAdd(&acc[0], wsum[0] + wsum[1] + wsum[2] + wsum[3]);
    }
}

// Kernel D: finalize means
__global__ void finalize_kernel(const double* __restrict__ acc, float* __restrict__ out)
{
    if (threadIdx.x == 0 && blockIdx.x == 0) {
        out[0] = (float)(acc[0] / (double)((long long)BB * NN * CC));
        out[1] = (float)(acc[1] / (double)(BB * GG * KK * 4));
        out[2] = (float)(acc[2] / (double)(BB * GG * KK));
    }
}

extern "C" void kernel_launch(void* const* d_in, const int* in_sizes, int n_in,
                              void* d_out, int out_size, void* d_ws, size_t ws_size,
                              hipStream_t stream) {
    const float* pred_logits = (const float*)d_in[0];  // (B,N,C)
    const float* pred_boxes  = (const float*)d_in[1];  // (B,N,4)
    const float* locations   = (const float*)d_in[2];  // (N,2)
    const float* gt_boxes    = (const float*)d_in[3];  // (B,G,4)
    const int*   gt_labels   = (const int*)d_in[4];    // (B,G)
    float* out = (float*)d_out;

    double* acc = (double*)d_ws;                  // 3 doubles at offset 0
    int* sel = (int*)((char*)d_ws + 64);          // B*G*K ints

    hipMemsetAsync(d_ws, 0, 64, stream);

    // A: 1024 pairs, one wave each, 4 per block
    topk_bbox_kernel<<<BB * GG / 4, 256, 0, stream>>>(locations, pred_boxes, gt_boxes, acc, sel);

    // B: focal main sum
    int nvec4 = (BB * NN * CC) / 4;
    focal_main_kernel<<<2048, 256, 0, stream>>>(pred_logits, acc, nvec4);

    // C: corrections (one block per image)
    correction_kernel<<<BB, 256, 0, stream>>>(pred_logits, sel, gt_labels, acc);

    // D: finalize
    finalize_kernel<<<1, 64, 0, stream>>>(acc, out);
}

// Round 6
// 335.740 us; speedup vs baseline: 1.4989x; 1.2875x over previous
//
#include <hip/hip_runtime.h>
#include <hip/hip_bf16.h>
#include <float.h>

// Problem constants (from setup_inputs): B=16, N=21504, C=80, G=64, K=9
#define BB 16
#define NN 21504
#define CC 80
#define GG 64
#define KK 9
#define NSEG 4
#define SEG4 (NN / 2 / NSEG)   // float4s per segment: 10752/4 = 2688
#define T4   (SEG4 / 64)       // 42 float4 iterations per lane

// ---------------- focal helpers ----------------
__device__ __forceinline__ float focal_t0(float x) {
    float ax = fabsf(x);
    float em = __expf(-ax);
    float sp = __logf(1.0f + em);
    float spx = fmaxf(x, 0.0f) + sp;     // softplus(x)
    float r = 1.0f / (1.0f + em);
    float p = (x >= 0.0f) ? r : em * r;  // sigmoid(x)
    return 0.75f * spx * p * p;
}

__device__ __forceinline__ float focal_corr(float x) {
    float ax = fabsf(x);
    float em = __expf(-ax);
    float sp = __logf(1.0f + em);
    float spx = fmaxf(x, 0.0f) + sp;
    float spn = fmaxf(-x, 0.0f) + sp;
    float r = 1.0f / (1.0f + em);
    float p = (x >= 0.0f) ? r : em * r;
    float q = 1.0f - p;
    float f1 = 0.25f * spn * q * q;
    float f0 = 0.75f * spx * p * p;
    return f1 - f0;
}

// one shared distance function so both scans produce bit-identical values
__device__ __forceinline__ float d2f(float cx, float cy, float x, float y) {
    float dx = cx - x, dy = cy - y;
    return dx * dx + dy * dy;
}

// Kernel A1: one wave per (pair, segment). Block = pair, wave = segment.
// Threshold top-9 within the segment (registers+shuffles only), writes the
// segment's 9 smallest (d2, n) to workspace.
__global__ __launch_bounds__(256) void topk_seg_kernel(
    const float* __restrict__ locations,   // (N,2)
    const float* __restrict__ gt_boxes,    // (B,G,4)
    float* __restrict__ cand_d,            // (1024*NSEG*KK)
    int*   __restrict__ cand_n)
{
    int seg  = threadIdx.x >> 6;           // 0..3
    int lane = threadIdx.x & 63;
    int pair = blockIdx.x;                 // 0..1023
    int b = pair >> 6;
    int g = pair & (GG - 1);

    const float4 gt = ((const float4*)gt_boxes)[b * GG + g];
    float cx = gt.x, cy = gt.y;
    const float4* loc4 = (const float4*)locations;
    int base4 = seg * SEG4 + lane;

    // Scan 1: per-lane min over 84 points (42 float4s, 2 pts each), 4-deep ILP
    float m0 = FLT_MAX, m1 = FLT_MAX, m2 = FLT_MAX, m3 = FLT_MAX;
#pragma unroll 4
    for (int t = 0; t < T4; t += 2) {
        float4 A = loc4[base4 + t * 64];
        float4 Bv = loc4[base4 + (t + 1) * 64];
        m0 = fminf(m0, d2f(cx, cy, A.x, A.y));
        m1 = fminf(m1, d2f(cx, cy, A.z, A.w));
        m2 = fminf(m2, d2f(cx, cy, Bv.x, Bv.y));
        m3 = fminf(m3, d2f(cx, cy, Bv.z, Bv.w));
    }
    float md = fminf(fminf(m0, m1), fminf(m2, m3));

    // T = 9th-smallest lane-min (ties only enlarge T -> superset, safe)
    float v = md;
    float T = FLT_MAX;
    for (int r = 0; r < KK; ++r) {
        float m = v;
        for (int s = 1; s < 64; s <<= 1) m = fminf(m, __shfl_xor(m, s));
        T = m;
        if (v == m) v = FLT_MAX;
    }

    // Scan 2: collect candidates d2 <= T, up to 6 per lane in named scalars
    float sd0 = FLT_MAX, sd1 = FLT_MAX, sd2 = FLT_MAX,
          sd3 = FLT_MAX, sd4 = FLT_MAX, sd5 = FLT_MAX;
    int   sn0 = 0x7fffffff, sn1 = 0x7fffffff, sn2 = 0x7fffffff,
          sn3 = 0x7fffffff, sn4 = 0x7fffffff, sn5 = 0x7fffffff;
    int cnt = 0;
#define PUSH(dv, nv)                                             \
    do {                                                         \
        if (cnt == 0)      { sd0 = dv; sn0 = nv; }               \
        else if (cnt == 1) { sd1 = dv; sn1 = nv; }               \
        else if (cnt == 2) { sd2 = dv; sn2 = nv; }               \
        else if (cnt == 3) { sd3 = dv; sn3 = nv; }               \
        else if (cnt == 4) { sd4 = dv; sn4 = nv; }               \
        else if (cnt == 5) { sd5 = dv; sn5 = nv; }               \
        ++cnt;                                                   \
    } while (0)

#pragma unroll 2
    for (int t = 0; t < T4; ++t) {
        int i4 = base4 + t * 64;
        float4 A = loc4[i4];
        float da = d2f(cx, cy, A.x, A.y);
        float db = d2f(cx, cy, A.z, A.w);
        if (da <= T) PUSH(da, 2 * i4);
        if (db <= T) PUSH(db, 2 * i4 + 1);
    }
#undef PUSH

    int ovf = (cnt > 6) ? 1 : 0;
    for (int s = 1; s < 64; s <<= 1) ovf = max(ovf, __shfl_xor(ovf, s));

    int obase = (pair * NSEG + seg) * KK;
    if (ovf == 0) {
        // 9 butterfly lex-min extraction rounds over the slots
        for (int r = 0; r < KK; ++r) {
            float bv = sd0; int bn = sn0;
            bool c;
            c = sd1 < bv; bv = c ? sd1 : bv; bn = c ? sn1 : bn;
            c = sd2 < bv; bv = c ? sd2 : bv; bn = c ? sn2 : bn;
            c = sd3 < bv; bv = c ? sd3 : bv; bn = c ? sn3 : bn;
            c = sd4 < bv; bv = c ? sd4 : bv; bn = c ? sn4 : bn;
            c = sd5 < bv; bv = c ? sd5 : bv; bn = c ? sn5 : bn;
            for (int s = 1; s < 64; s <<= 1) {
                float ov = __shfl_xor(bv, s);
                int   on = __shfl_xor(bn, s);
                bool cc = (ov < bv) || (ov == bv && on < bn);
                bv = cc ? ov : bv;
                bn = cc ? on : bn;
            }
            if (sn0 == bn) sd0 = FLT_MAX;
            if (sn1 == bn) sd1 = FLT_MAX;
            if (sn2 == bn) sd2 = FLT_MAX;
            if (sn3 == bn) sd3 = FLT_MAX;
            if (sn4 == bn) sd4 = FLT_MAX;
            if (sn5 == bn) sd5 = FLT_MAX;
            if (lane == 0) { cand_d[obase + r] = bv; cand_n[obase + r] = bn; }
        }
    } else {
        // rare exact fallback: 9 lex-min rescans of this segment
        float lastD = -1.0f; int lastN = -1;
        for (int r = 0; r < KK; ++r) {
            float bv = FLT_MAX; int bn = 0x7fffffff;
            for (int t = 0; t < T4; ++t) {
                int i4 = base4 + t * 64;
                float4 A = loc4[i4];
                float da = d2f(cx, cy, A.x, A.y);
                float db = d2f(cx, cy, A.z, A.w);
                int na = 2 * i4, nb = 2 * i4 + 1;
                bool ga = (da > lastD) || (da == lastD && na > lastN);
                bool ca = ga && ((da < bv) || (da == bv && na < bn));
                bv = ca ? da : bv; bn = ca ? na : bn;
                bool gb = (db > lastD) || (db == lastD && nb > lastN);
                bool cb = gb && ((db < bv) || (db == bv && nb < bn));
                bv = cb ? db : bv; bn = cb ? nb : bn;
            }
            for (int s = 1; s < 64; s <<= 1) {
                float ov = __shfl_xor(bv, s);
                int   on = __shfl_xor(bn, s);
                bool cc = (ov < bv) || (ov == bv && on < bn);
                bv = cc ? ov : bv;
                bn = cc ? on : bn;
            }
            lastD = bv; lastN = bn;
            if (lane == 0) { cand_d[obase + r] = bv; cand_n[obase + r] = bn; }
        }
    }
}

// Kernel A2: one wave per pair merges 36 candidates (one per lane),
// extracts the global top-9 and does the bbox L1 + GIoU epilogue.
__global__ __launch_bounds__(256) void topk_merge_kernel(
    const float* __restrict__ pred_boxes,  // (B,N,4)
    const float* __restrict__ gt_boxes,    // (B,G,4)
    const float* __restrict__ cand_d,
    const int*   __restrict__ cand_n,
    double* __restrict__ acc,
    int* __restrict__ sel)
{
    int wv   = threadIdx.x >> 6;
    int lane = threadIdx.x & 63;
    int pair = blockIdx.x * 4 + wv;        // 0..1023
    int b = pair >> 6;
    int g = pair & (GG - 1);

    const float4 gt = ((const float4*)gt_boxes)[b * GG + g];

    float vd = FLT_MAX; int vn = 0x7fffffff;
    if (lane < NSEG * KK) {
        vd = cand_d[pair * NSEG * KK + lane];
        vn = cand_n[pair * NSEG * KK + lane];
    }

    int myn = 0;
    for (int r = 0; r < KK; ++r) {
        float bv = vd; int bn = vn;
        for (int s = 1; s < 64; s <<= 1) {
            float ov = __shfl_xor(bv, s);
            int   on = __shfl_xor(bn, s);
            bool cc = (ov < bv) || (ov == bv && on < bn);
            bv = cc ? ov : bv;
            bn = cc ? on : bn;
        }
        if (vn == bn) vd = FLT_MAX;   // n unique across lanes
        if (lane == r) myn = bn;
        if (lane == 0) sel[pair * KK + r] = bn;
    }
    myn = myn < 0 ? 0 : (myn >= NN ? NN - 1 : myn);  // fault guard

    float l1 = 0.0f, gio = 0.0f;
    if (lane < KK) {
        float4 p = ((const float4*)pred_boxes)[b * NN + myn];
        l1 = fabsf(p.x - gt.x) + fabsf(p.y - gt.y) + fabsf(p.z - gt.z) + fabsf(p.w - gt.w);

        float ax1 = p.x - 0.5f * p.z, ay1 = p.y - 0.5f * p.w;
        float ax2 = p.x + 0.5f * p.z, ay2 = p.y + 0.5f * p.w;
        float bx1 = gt.x - 0.5f * gt.z, by1 = gt.y - 0.5f * gt.w;
        float bx2 = gt.x + 0.5f * gt.z, by2 = gt.y + 0.5f * gt.w;

        float area_a = (ax2 - ax1) * (ay2 - ay1);
        float area_b = (bx2 - bx1) * (by2 - by1);
        float ix1 = fmaxf(ax1, bx1), iy1 = fmaxf(ay1, by1);
        float ix2 = fminf(ax2, bx2), iy2 = fminf(ay2, by2);
        float iw = fmaxf(ix2 - ix1, 0.0f), ih = fmaxf(iy2 - iy1, 0.0f);
        float inter = iw * ih;
        float uni = area_a + area_b - inter;
        float iou = inter / uni;
        float ccx1 = fminf(ax1, bx1), ccy1 = fminf(ay1, by1);
        float ccx2 = fmaxf(ax2, bx2), ccy2 = fmaxf(ay2, by2);
        float cw = fmaxf(ccx2 - ccx1, 0.0f), ch = fmaxf(ccy2 - ccy1, 0.0f);
        float ac = cw * ch;
        float giou = iou - (ac - uni) / ac;
        gio = 1.0f - giou;
    }
    for (int o = 32; o > 0; o >>= 1) {
        l1 += __shfl_down(l1, o);
        gio += __shfl_down(gio, o);
    }
    if (lane == 0) {
        atomicAdd(&acc[1], (double)l1);
        atomicAdd(&acc[2], (double)gio);
    }
}

// Kernel B: main focal sum over all B*N*C logits (t=0 formula everywhere)
__global__ __launch_bounds__(256) void focal_main_kernel(
    const float* __restrict__ logits, double* __restrict__ acc, int nvec4)
{
    const float4* v = (const float4*)logits;
    float s0 = 0.f, s1 = 0.f, s2 = 0.f, s3 = 0.f;
    int stride = gridDim.x * blockDim.x;
    for (int i = blockIdx.x * blockDim.x + threadIdx.x; i < nvec4; i += stride) {
        float4 x = v[i];
        s0 += focal_t0(x.x);
        s1 += focal_t0(x.y);
        s2 += focal_t0(x.z);
        s3 += focal_t0(x.w);
    }
    double d = (double)((s0 + s1) + (s2 + s3));
#pragma unroll
    for (int o = 32; o > 0; o >>= 1) d += __shfl_down(d, o);
    __shared__ double wsum[4];
    if ((threadIdx.x & 63) == 0) wsum[threadIdx.x >> 6] = d;
    __syncthreads();
    if (threadIdx.x == 0) {
        atomicAdd(&acc[0], wsum[0] + wsum[1] + wsum[2] + wsum[3]);
    }
}

// Kernel C: per-image dedup of the 576 selected (n, class) keys, apply
// focal correction f1-f0 once per unique key.
__global__ __launch_bounds__(256) void correction_kernel(
    const float* __restrict__ logits, const int* __restrict__ sel,
    const int* __restrict__ gt_labels, double* __restrict__ acc)
{
    int b = blockIdx.x;
    __shared__ int keys[GG * KK];
    for (int e = threadIdx.x; e < GG * KK; e += blockDim.x) {
        int g = e / KK;
        int n = sel[(b * GG + g) * KK + (e - g * KK)];
        keys[e] = n * CC + gt_labels[b * GG + g];
    }
    __syncthreads();

    float corr = 0.0f;
    for (int e = threadIdx.x; e < GG * KK; e += blockDim.x) {
        int k = keys[e];
        bool uniq = true;
        for (int e2 = 0; e2 < e; ++e2) {
            if (keys[e2] == k) { uniq = false; break; }
        }
        if (uniq) {
            float x = logits[b * NN * CC + k];
            corr += focal_corr(x);
        }
    }
    double d = (double)corr;
#pragma unroll
    for (int o = 32; o > 0; o >>= 1) d += __shfl_down(d, o);
    __shared__ double wsum[4];
    if ((threadIdx.x & 63) == 0) wsum[threadIdx.x >> 6] = d;
    __syncthreads();
    if (threadIdx.x == 0) {
        atomicAdd(&acc[0], wsum[0] + wsum[1] + wsum[2] + wsum[3]);
    }
}

// Kernel D: finalize means
__global__ void finalize_kernel(const double* __restrict__ acc, float* __restrict__ out)
{
    if (threadIdx.x == 0 && blockIdx.x == 0) {
        out[0] = (float)(acc[0] / (double)((long long)BB * NN * CC));
        out[1] = (float)(acc[1] / (double)(BB * GG * KK * 4));
        out[2] = (float)(acc[2] / (double)(BB * GG * KK));
    }
}

extern "C" void kernel_launch(void* const* d_in, const int* in_sizes, int n_in,
                              void* d_out, int out_size, void* d_ws, size_t ws_size,
                              hipStream_t stream) {
    const float* pred_logits = (const float*)d_in[0];  // (B,N,C)
    const float* pred_boxes  = (const float*)d_in[1];  // (B,N,4)
    const float* locations   = (const float*)d_in[2];  // (N,2)
    const float* gt_boxes    = (const float*)d_in[3];  // (B,G,4)
    const int*   gt_labels   = (const int*)d_in[4];    // (B,G)
    float* out = (float*)d_out;

    // workspace layout
    double* acc   = (double*)d_ws;                         // 3 doubles
    int*    sel   = (int*)((char*)d_ws + 64);              // 1024*9 ints  = 36864 B
    float*  candd = (float*)((char*)d_ws + 64 + 36864);    // 4096*9 floats = 147456 B
    int*    candn = (int*)((char*)d_ws + 64 + 36864 + 147456);

    hipMemsetAsync(d_ws, 0, 64, stream);

    // A1: per-segment top-9 (1024 blocks x 4 waves = 4096 wave-segments)
    topk_seg_kernel<<<BB * GG, 256, 0, stream>>>(locations, gt_boxes, candd, candn);

    // A2: merge 36 candidates/pair + bbox epilogue (256 blocks x 4 waves)
    topk_merge_kernel<<<BB * GG / 4, 256, 0, stream>>>(pred_boxes, gt_boxes, candd, candn, acc, sel);

    // B: focal main sum
    int nvec4 = (BB * NN * CC) / 4;
    focal_main_kernel<<<2048, 256, 0, stream>>>(pred_logits, acc, nvec4);

    // C: corrections (one block per image)
    correction_kernel<<<BB, 256, 0, stream>>>(pred_logits, sel, gt_labels, acc);

    // D: finalize
    finalize_kernel<<<1, 64, 0, stream>>>(acc, out);
}

// Round 7
// 287.510 us; speedup vs baseline: 1.7503x; 1.1678x over previous
//
#include <hip/hip_runtime.h>
#include <hip/hip_bf16.h>
#include <float.h>

// Problem constants (from setup_inputs): B=16, N=21504, C=80, G=64, K=9
#define BB 16
#define NN 21504
#define CC 80
#define GG 64
#define KK 9
#define NSEG 4
#define SEG4 (NN / 2 / NSEG)   // float4s per segment: 10752/4 = 2688
#define T4   (SEG4 / 64)       // 42 float4 iterations per lane

// ---------------- focal helpers ----------------
__device__ __forceinline__ float focal_t0(float x) {
    float ax = fabsf(x);
    float em = __expf(-ax);
    float sp = __logf(1.0f + em);
    float spx = fmaxf(x, 0.0f) + sp;     // softplus(x)
    float r = 1.0f / (1.0f + em);
    float p = (x >= 0.0f) ? r : em * r;  // sigmoid(x)
    return 0.75f * spx * p * p;
}

__device__ __forceinline__ float focal_corr(float x) {
    float ax = fabsf(x);
    float em = __expf(-ax);
    float sp = __logf(1.0f + em);
    float spx = fmaxf(x, 0.0f) + sp;
    float spn = fmaxf(-x, 0.0f) + sp;
    float r = 1.0f / (1.0f + em);
    float p = (x >= 0.0f) ? r : em * r;
    float q = 1.0f - p;
    float f1 = 0.25f * spn * q * q;
    float f0 = 0.75f * spx * p * p;
    return f1 - f0;
}

// one shared distance function so both scans produce bit-identical values
__device__ __forceinline__ float d2f(float cx, float cy, float x, float y) {
    float dx = cx - x, dy = cy - y;
    return dx * dx + dy * dy;
}

// Kernel A1: one wave per (pair, segment). Block = pair, wave = segment.
// Threshold top-9 within the segment (registers+shuffles only), writes the
// segment's 9 smallest (d2, n) to workspace.
__global__ __launch_bounds__(256) void topk_seg_kernel(
    const float* __restrict__ locations,   // (N,2)
    const float* __restrict__ gt_boxes,    // (B,G,4)
    float* __restrict__ cand_d,            // (1024*NSEG*KK)
    int*   __restrict__ cand_n)
{
    int seg  = threadIdx.x >> 6;           // 0..3
    int lane = threadIdx.x & 63;
    int pair = blockIdx.x;                 // 0..1023
    int b = pair >> 6;
    int g = pair & (GG - 1);

    const float4 gt = ((const float4*)gt_boxes)[b * GG + g];
    float cx = gt.x, cy = gt.y;
    const float4* loc4 = (const float4*)locations;
    int base4 = seg * SEG4 + lane;

    // Scan 1: per-lane min over 84 points (42 float4s, 2 pts each), 4-deep ILP
    float m0 = FLT_MAX, m1 = FLT_MAX, m2 = FLT_MAX, m3 = FLT_MAX;
#pragma unroll 4
    for (int t = 0; t < T4; t += 2) {
        float4 A = loc4[base4 + t * 64];
        float4 Bv = loc4[base4 + (t + 1) * 64];
        m0 = fminf(m0, d2f(cx, cy, A.x, A.y));
        m1 = fminf(m1, d2f(cx, cy, A.z, A.w));
        m2 = fminf(m2, d2f(cx, cy, Bv.x, Bv.y));
        m3 = fminf(m3, d2f(cx, cy, Bv.z, Bv.w));
    }
    float md = fminf(fminf(m0, m1), fminf(m2, m3));

    // T = 9th-smallest lane-min (ties only enlarge T -> superset, safe)
    float v = md;
    float T = FLT_MAX;
    for (int r = 0; r < KK; ++r) {
        float m = v;
        for (int s = 1; s < 64; s <<= 1) m = fminf(m, __shfl_xor(m, s));
        T = m;
        if (v == m) v = FLT_MAX;
    }

    // Scan 2: collect candidates d2 <= T, up to 6 per lane in named scalars
    float sd0 = FLT_MAX, sd1 = FLT_MAX, sd2 = FLT_MAX,
          sd3 = FLT_MAX, sd4 = FLT_MAX, sd5 = FLT_MAX;
    int   sn0 = 0x7fffffff, sn1 = 0x7fffffff, sn2 = 0x7fffffff,
          sn3 = 0x7fffffff, sn4 = 0x7fffffff, sn5 = 0x7fffffff;
    int cnt = 0;
#define PUSH(dv, nv)                                             \
    do {                                                         \
        if (cnt == 0)      { sd0 = dv; sn0 = nv; }               \
        else if (cnt == 1) { sd1 = dv; sn1 = nv; }               \
        else if (cnt == 2) { sd2 = dv; sn2 = nv; }               \
        else if (cnt == 3) { sd3 = dv; sn3 = nv; }               \
        else if (cnt == 4) { sd4 = dv; sn4 = nv; }               \
        else if (cnt == 5) { sd5 = dv; sn5 = nv; }               \
        ++cnt;                                                   \
    } while (0)

#pragma unroll 2
    for (int t = 0; t < T4; ++t) {
        int i4 = base4 + t * 64;
        float4 A = loc4[i4];
        float da = d2f(cx, cy, A.x, A.y);
        float db = d2f(cx, cy, A.z, A.w);
        if (da <= T) PUSH(da, 2 * i4);
        if (db <= T) PUSH(db, 2 * i4 + 1);
    }
#undef PUSH

    int ovf = (cnt > 6) ? 1 : 0;
    for (int s = 1; s < 64; s <<= 1) ovf = max(ovf, __shfl_xor(ovf, s));

    int obase = (pair * NSEG + seg) * KK;
    if (ovf == 0) {
        // 9 butterfly lex-min extraction rounds over the slots
        for (int r = 0; r < KK; ++r) {
            float bv = sd0; int bn = sn0;
            bool c;
            c = sd1 < bv; bv = c ? sd1 : bv; bn = c ? sn1 : bn;
            c = sd2 < bv; bv = c ? sd2 : bv; bn = c ? sn2 : bn;
            c = sd3 < bv; bv = c ? sd3 : bv; bn = c ? sn3 : bn;
            c = sd4 < bv; bv = c ? sd4 : bv; bn = c ? sn4 : bn;
            c = sd5 < bv; bv = c ? sd5 : bv; bn = c ? sn5 : bn;
            for (int s = 1; s < 64; s <<= 1) {
                float ov = __shfl_xor(bv, s);
                int   on = __shfl_xor(bn, s);
                bool cc = (ov < bv) || (ov == bv && on < bn);
                bv = cc ? ov : bv;
                bn = cc ? on : bn;
            }
            if (sn0 == bn) sd0 = FLT_MAX;
            if (sn1 == bn) sd1 = FLT_MAX;
            if (sn2 == bn) sd2 = FLT_MAX;
            if (sn3 == bn) sd3 = FLT_MAX;
            if (sn4 == bn) sd4 = FLT_MAX;
            if (sn5 == bn) sd5 = FLT_MAX;
            if (lane == 0) { cand_d[obase + r] = bv; cand_n[obase + r] = bn; }
        }
    } else {
        // rare exact fallback: 9 lex-min rescans of this segment
        float lastD = -1.0f; int lastN = -1;
        for (int r = 0; r < KK; ++r) {
            float bv = FLT_MAX; int bn = 0x7fffffff;
            for (int t = 0; t < T4; ++t) {
                int i4 = base4 + t * 64;
                float4 A = loc4[i4];
                float da = d2f(cx, cy, A.x, A.y);
                float db = d2f(cx, cy, A.z, A.w);
                int na = 2 * i4, nb = 2 * i4 + 1;
                bool ga = (da > lastD) || (da == lastD && na > lastN);
                bool ca = ga && ((da < bv) || (da == bv && na < bn));
                bv = ca ? da : bv; bn = ca ? na : bn;
                bool gb = (db > lastD) || (db == lastD && nb > lastN);
                bool cb = gb && ((db < bv) || (db == bv && nb < bn));
                bv = cb ? db : bv; bn = cb ? nb : bn;
            }
            for (int s = 1; s < 64; s <<= 1) {
                float ov = __shfl_xor(bv, s);
                int   on = __shfl_xor(bn, s);
                bool cc = (ov < bv) || (ov == bv && on < bn);
                bv = cc ? ov : bv;
                bn = cc ? on : bn;
            }
            lastD = bv; lastN = bn;
            if (lane == 0) { cand_d[obase + r] = bv; cand_n[obase + r] = bn; }
        }
    }
}

// Kernel A2: one wave per pair merges 36 candidates (one per lane),
// extracts the global top-9 and does the bbox L1 + GIoU epilogue.
__global__ __launch_bounds__(256) void topk_merge_kernel(
    const float* __restrict__ pred_boxes,  // (B,N,4)
    const float* __restrict__ gt_boxes,    // (B,G,4)
    const float* __restrict__ cand_d,
    const int*   __restrict__ cand_n,
    double* __restrict__ acc,
    int* __restrict__ sel)
{
    int wv   = threadIdx.x >> 6;
    int lane = threadIdx.x & 63;
    int pair = blockIdx.x * 4 + wv;        // 0..1023
    int b = pair >> 6;
    int g = pair & (GG - 1);

    const float4 gt = ((const float4*)gt_boxes)[b * GG + g];

    float vd = FLT_MAX; int vn = 0x7fffffff;
    if (lane < NSEG * KK) {
        vd = cand_d[pair * NSEG * KK + lane];
        vn = cand_n[pair * NSEG * KK + lane];
    }

    int myn = 0;
    for (int r = 0; r < KK; ++r) {
        float bv = vd; int bn = vn;
        for (int s = 1; s < 64; s <<= 1) {
            float ov = __shfl_xor(bv, s);
            int   on = __shfl_xor(bn, s);
            bool cc = (ov < bv) || (ov == bv && on < bn);
            bv = cc ? ov : bv;
            bn = cc ? on : bn;
        }
        if (vn == bn) vd = FLT_MAX;   // n unique across lanes
        if (lane == r) myn = bn;
        if (lane == 0) sel[pair * KK + r] = bn;
    }
    myn = myn < 0 ? 0 : (myn >= NN ? NN - 1 : myn);  // fault guard

    float l1 = 0.0f, gio = 0.0f;
    if (lane < KK) {
        float4 p = ((const float4*)pred_boxes)[b * NN + myn];
        l1 = fabsf(p.x - gt.x) + fabsf(p.y - gt.y) + fabsf(p.z - gt.z) + fabsf(p.w - gt.w);

        float ax1 = p.x - 0.5f * p.z, ay1 = p.y - 0.5f * p.w;
        float ax2 = p.x + 0.5f * p.z, ay2 = p.y + 0.5f * p.w;
        float bx1 = gt.x - 0.5f * gt.z, by1 = gt.y - 0.5f * gt.w;
        float bx2 = gt.x + 0.5f * gt.z, by2 = gt.y + 0.5f * gt.w;

        float area_a = (ax2 - ax1) * (ay2 - ay1);
        float area_b = (bx2 - bx1) * (by2 - by1);
        float ix1 = fmaxf(ax1, bx1), iy1 = fmaxf(ay1, by1);
        float ix2 = fminf(ax2, bx2), iy2 = fminf(ay2, by2);
        float iw = fmaxf(ix2 - ix1, 0.0f), ih = fmaxf(iy2 - iy1, 0.0f);
        float inter = iw * ih;
        float uni = area_a + area_b - inter;
        float iou = inter / uni;
        float ccx1 = fminf(ax1, bx1), ccy1 = fminf(ay1, by1);
        float ccx2 = fmaxf(ax2, bx2), ccy2 = fmaxf(ay2, by2);
        float cw = fmaxf(ccx2 - ccx1, 0.0f), ch = fmaxf(ccy2 - ccy1, 0.0f);
        float ac = cw * ch;
        float giou = iou - (ac - uni) / ac;
        gio = 1.0f - giou;
    }
    for (int o = 32; o > 0; o >>= 1) {
        l1 += __shfl_down(l1, o);
        gio += __shfl_down(gio, o);
    }
    if (lane == 0) {
        atomicAdd(&acc[1], (double)l1);
        atomicAdd(&acc[2], (double)gio);
    }
}

// Kernel B: main focal sum over all B*N*C logits (t=0 formula everywhere)
__global__ __launch_bounds__(256) void focal_main_kernel(
    const float* __restrict__ logits, double* __restrict__ acc, int nvec4)
{
    const float4* v = (const float4*)logits;
    float s0 = 0.f, s1 = 0.f, s2 = 0.f, s3 = 0.f;
    int stride = gridDim.x * blockDim.x;
    for (int i = blockIdx.x * blockDim.x + threadIdx.x; i < nvec4; i += stride) {
        float4 x = v[i];
        s0 += focal_t0(x.x);
        s1 += focal_t0(x.y);
        s2 += focal_t0(x.z);
        s3 += focal_t0(x.w);
    }
    double d = (double)((s0 + s1) + (s2 + s3));
#pragma unroll
    for (int o = 32; o > 0; o >>= 1) d += __shfl_down(d, o);
    __shared__ double wsum[4];
    if ((threadIdx.x & 63) == 0) wsum[threadIdx.x >> 6] = d;
    __syncthreads();
    if (threadIdx.x == 0) {
        atomicAdd(&acc[0], wsum[0] + wsum[1] + wsum[2] + wsum[3]);
    }
}

// Kernel C (v2): 4 blocks per image. Branchless dedup: uniform 576-trip
// broadcast scan of LDS keys (no break, no divergence, no LDS conflicts).
// Each of threads 0..143 owns one element e; unique keys get focal_corr.
#define EPB 144   // elements per block (576 / 4)
__global__ __launch_bounds__(256) void correction_kernel(
    const float* __restrict__ logits, const int* __restrict__ sel,
    const int* __restrict__ gt_labels, double* __restrict__ acc)
{
    int bq = blockIdx.x;           // 0..63
    int b  = bq >> 2;              // image
    int q  = bq & 3;               // quarter

    __shared__ int keys[GG * KK];
    for (int e = threadIdx.x; e < GG * KK; e += blockDim.x) {
        int g = e / KK;
        int n = sel[(b * GG + g) * KK + (e - g * KK)];
        keys[e] = n * CC + gt_labels[b * GG + g];
    }
    __syncthreads();

    int e = q * EPB + threadIdx.x;            // threads >= EPB idle
    bool active = (threadIdx.x < EPB);
    int k = active ? keys[e] : -1;

    // branchless duplicate test: dup = OR over e2 < e of (keys[e2] == k).
    // Uniform trip count; all lanes read the same keys[e2] -> LDS broadcast.
    bool dup = false;
#pragma unroll 8
    for (int e2 = 0; e2 < GG * KK; ++e2) {
        dup = dup || (e2 < e && keys[e2] == k);
    }

    float corr = 0.0f;
    if (active && !dup) {
        corr = focal_corr(logits[(long long)b * NN * CC + k]);
    }

    double d = (double)corr;
#pragma unroll
    for (int o = 32; o > 0; o >>= 1) d += __shfl_down(d, o);
    __shared__ double wsum[4];
    if ((threadIdx.x & 63) == 0) wsum[threadIdx.x >> 6] = d;
    __syncthreads();
    if (threadIdx.x == 0) {
        atomicAdd(&acc[0], wsum[0] + wsum[1] + wsum[2] + wsum[3]);
    }
}

// Kernel D: finalize means
__global__ void finalize_kernel(const double* __restrict__ acc, float* __restrict__ out)
{
    if (threadIdx.x == 0 && blockIdx.x == 0) {
        out[0] = (float)(acc[0] / (double)((long long)BB * NN * CC));
        out[1] = (float)(acc[1] / (double)(BB * GG * KK * 4));
        out[2] = (float)(acc[2] / (double)(BB * GG * KK));
    }
}

extern "C" void kernel_launch(void* const* d_in, const int* in_sizes, int n_in,
                              void* d_out, int out_size, void* d_ws, size_t ws_size,
                              hipStream_t stream) {
    const float* pred_logits = (const float*)d_in[0];  // (B,N,C)
    const float* pred_boxes  = (const float*)d_in[1];  // (B,N,4)
    const float* locations   = (const float*)d_in[2];  // (N,2)
    const float* gt_boxes    = (const float*)d_in[3];  // (B,G,4)
    const int*   gt_labels   = (const int*)d_in[4];    // (B,G)
    float* out = (float*)d_out;

    // workspace layout
    double* acc   = (double*)d_ws;                         // 3 doubles
    int*    sel   = (int*)((char*)d_ws + 64);              // 1024*9 ints  = 36864 B
    float*  candd = (float*)((char*)d_ws + 64 + 36864);    // 4096*9 floats = 147456 B
    int*    candn = (int*)((char*)d_ws + 64 + 36864 + 147456);

    hipMemsetAsync(d_ws, 0, 64, stream);

    // A1: per-segment top-9 (1024 blocks x 4 waves = 4096 wave-segments)
    topk_seg_kernel<<<BB * GG, 256, 0, stream>>>(locations, gt_boxes, candd, candn);

    // A2: merge 36 candidates/pair + bbox epilogue (256 blocks x 4 waves)
    topk_merge_kernel<<<BB * GG / 4, 256, 0, stream>>>(pred_boxes, gt_boxes, candd, candn, acc, sel);

    // B: focal main sum
    int nvec4 = (BB * NN * CC) / 4;
    focal_main_kernel<<<2048, 256, 0, stream>>>(pred_logits, acc, nvec4);

    // C: corrections (4 blocks per image)
    correction_kernel<<<BB * 4, 256, 0, stream>>>(pred_logits, sel, gt_labels, acc);

    // D: finalize
    finalize_kernel<<<1, 64, 0, stream>>>(acc, out);
}

// Round 8
// 255.884 us; speedup vs baseline: 1.9667x; 1.1236x over previous
//
#include <hip/hip_runtime.h>
#include <hip/hip_bf16.h>
#include <float.h>

// Problem constants (from setup_inputs): B=16, N=21504, C=80, G=64, K=9
#define BB 16
#define NN 21504
#define CC 80
#define GG 64
#define KK 9
#define NSEG 4
#define SEG4 (NN / 2 / NSEG)   // float4s per segment: 10752/4 = 2688
#define T4   (SEG4 / 64)       // 42 float4 iterations per lane

// ---------------- focal helpers ----------------
__device__ __forceinline__ float focal_t0(float x) {
    float ax = fabsf(x);
    float em = __expf(-ax);
    float sp = __logf(1.0f + em);
    float spx = fmaxf(x, 0.0f) + sp;     // softplus(x)
    float r = 1.0f / (1.0f + em);
    float p = (x >= 0.0f) ? r : em * r;  // sigmoid(x)
    return 0.75f * spx * p * p;
}

__device__ __forceinline__ float focal_corr(float x) {
    float ax = fabsf(x);
    float em = __expf(-ax);
    float sp = __logf(1.0f + em);
    float spx = fmaxf(x, 0.0f) + sp;
    float spn = fmaxf(-x, 0.0f) + sp;
    float r = 1.0f / (1.0f + em);
    float p = (x >= 0.0f) ? r : em * r;
    float q = 1.0f - p;
    float f1 = 0.25f * spn * q * q;
    float f0 = 0.75f * spx * p * p;
    return f1 - f0;
}

// one shared distance function so both scans produce bit-identical values
__device__ __forceinline__ float d2f(float cx, float cy, float x, float y) {
    float dx = cx - x, dy = cy - y;
    return dx * dx + dy * dy;
}

// Kernel A1: one wave per (pair, segment). Block = pair, wave = segment.
// Threshold top-9 within the segment (registers+shuffles only), writes the
// segment's 9 smallest (d2, n) to workspace.
__global__ __launch_bounds__(256) void topk_seg_kernel(
    const float* __restrict__ locations,   // (N,2)
    const float* __restrict__ gt_boxes,    // (B,G,4)
    float* __restrict__ cand_d,            // (1024*NSEG*KK)
    int*   __restrict__ cand_n)
{
    int seg  = threadIdx.x >> 6;           // 0..3
    int lane = threadIdx.x & 63;
    int pair = blockIdx.x;                 // 0..1023
    int b = pair >> 6;
    int g = pair & (GG - 1);

    const float4 gt = ((const float4*)gt_boxes)[b * GG + g];
    float cx = gt.x, cy = gt.y;
    const float4* loc4 = (const float4*)locations;
    int base4 = seg * SEG4 + lane;

    // Scan 1: per-lane min over 84 points (42 float4s, 2 pts each), 4-deep ILP
    float m0 = FLT_MAX, m1 = FLT_MAX, m2 = FLT_MAX, m3 = FLT_MAX;
#pragma unroll 4
    for (int t = 0; t < T4; t += 2) {
        float4 A = loc4[base4 + t * 64];
        float4 Bv = loc4[base4 + (t + 1) * 64];
        m0 = fminf(m0, d2f(cx, cy, A.x, A.y));
        m1 = fminf(m1, d2f(cx, cy, A.z, A.w));
        m2 = fminf(m2, d2f(cx, cy, Bv.x, Bv.y));
        m3 = fminf(m3, d2f(cx, cy, Bv.z, Bv.w));
    }
    float md = fminf(fminf(m0, m1), fminf(m2, m3));

    // T = 9th-smallest lane-min (ties only enlarge T -> superset, safe)
    float v = md;
    float T = FLT_MAX;
    for (int r = 0; r < KK; ++r) {
        float m = v;
        for (int s = 1; s < 64; s <<= 1) m = fminf(m, __shfl_xor(m, s));
        T = m;
        if (v == m) v = FLT_MAX;
    }

    // Scan 2: collect candidates d2 <= T, up to 6 per lane in named scalars
    float sd0 = FLT_MAX, sd1 = FLT_MAX, sd2 = FLT_MAX,
          sd3 = FLT_MAX, sd4 = FLT_MAX, sd5 = FLT_MAX;
    int   sn0 = 0x7fffffff, sn1 = 0x7fffffff, sn2 = 0x7fffffff,
          sn3 = 0x7fffffff, sn4 = 0x7fffffff, sn5 = 0x7fffffff;
    int cnt = 0;
#define PUSH(dv, nv)                                             \
    do {                                                         \
        if (cnt == 0)      { sd0 = dv; sn0 = nv; }               \
        else if (cnt == 1) { sd1 = dv; sn1 = nv; }               \
        else if (cnt == 2) { sd2 = dv; sn2 = nv; }               \
        else if (cnt == 3) { sd3 = dv; sn3 = nv; }               \
        else if (cnt == 4) { sd4 = dv; sn4 = nv; }               \
        else if (cnt == 5) { sd5 = dv; sn5 = nv; }               \
        ++cnt;                                                   \
    } while (0)

#pragma unroll 2
    for (int t = 0; t < T4; ++t) {
        int i4 = base4 + t * 64;
        float4 A = loc4[i4];
        float da = d2f(cx, cy, A.x, A.y);
        float db = d2f(cx, cy, A.z, A.w);
        if (da <= T) PUSH(da, 2 * i4);
        if (db <= T) PUSH(db, 2 * i4 + 1);
    }
#undef PUSH

    int ovf = (cnt > 6) ? 1 : 0;
    for (int s = 1; s < 64; s <<= 1) ovf = max(ovf, __shfl_xor(ovf, s));

    int obase = (pair * NSEG + seg) * KK;
    if (ovf == 0) {
        // 9 butterfly lex-min extraction rounds over the slots
        for (int r = 0; r < KK; ++r) {
            float bv = sd0; int bn = sn0;
            bool c;
            c = sd1 < bv; bv = c ? sd1 : bv; bn = c ? sn1 : bn;
            c = sd2 < bv; bv = c ? sd2 : bv; bn = c ? sn2 : bn;
            c = sd3 < bv; bv = c ? sd3 : bv; bn = c ? sn3 : bn;
            c = sd4 < bv; bv = c ? sd4 : bv; bn = c ? sn4 : bn;
            c = sd5 < bv; bv = c ? sd5 : bv; bn = c ? sn5 : bn;
            for (int s = 1; s < 64; s <<= 1) {
                float ov = __shfl_xor(bv, s);
                int   on = __shfl_xor(bn, s);
                bool cc = (ov < bv) || (ov == bv && on < bn);
                bv = cc ? ov : bv;
                bn = cc ? on : bn;
            }
            if (sn0 == bn) sd0 = FLT_MAX;
            if (sn1 == bn) sd1 = FLT_MAX;
            if (sn2 == bn) sd2 = FLT_MAX;
            if (sn3 == bn) sd3 = FLT_MAX;
            if (sn4 == bn) sd4 = FLT_MAX;
            if (sn5 == bn) sd5 = FLT_MAX;
            if (lane == 0) { cand_d[obase + r] = bv; cand_n[obase + r] = bn; }
        }
    } else {
        // rare exact fallback: 9 lex-min rescans of this segment
        float lastD = -1.0f; int lastN = -1;
        for (int r = 0; r < KK; ++r) {
            float bv = FLT_MAX; int bn = 0x7fffffff;
            for (int t = 0; t < T4; ++t) {
                int i4 = base4 + t * 64;
                float4 A = loc4[i4];
                float da = d2f(cx, cy, A.x, A.y);
                float db = d2f(cx, cy, A.z, A.w);
                int na = 2 * i4, nb = 2 * i4 + 1;
                bool ga = (da > lastD) || (da == lastD && na > lastN);
                bool ca = ga && ((da < bv) || (da == bv && na < bn));
                bv = ca ? da : bv; bn = ca ? na : bn;
                bool gb = (db > lastD) || (db == lastD && nb > lastN);
                bool cb = gb && ((db < bv) || (db == bv && nb < bn));
                bv = cb ? db : bv; bn = cb ? nb : bn;
            }
            for (int s = 1; s < 64; s <<= 1) {
                float ov = __shfl_xor(bv, s);
                int   on = __shfl_xor(bn, s);
                bool cc = (ov < bv) || (ov == bv && on < bn);
                bv = cc ? ov : bv;
                bn = cc ? on : bn;
            }
            lastD = bv; lastN = bn;
            if (lane == 0) { cand_d[obase + r] = bv; cand_n[obase + r] = bn; }
        }
    }
}

// Kernel A2: one wave per pair merges 36 candidates (one per lane),
// extracts the global top-9 and does the bbox L1 + GIoU epilogue.
__global__ __launch_bounds__(256) void topk_merge_kernel(
    const float* __restrict__ pred_boxes,  // (B,N,4)
    const float* __restrict__ gt_boxes,    // (B,G,4)
    const float* __restrict__ cand_d,
    const int*   __restrict__ cand_n,
    double* __restrict__ acc,
    int* __restrict__ sel)
{
    int wv   = threadIdx.x >> 6;
    int lane = threadIdx.x & 63;
    int pair = blockIdx.x * 4 + wv;        // 0..1023
    int b = pair >> 6;
    int g = pair & (GG - 1);

    const float4 gt = ((const float4*)gt_boxes)[b * GG + g];

    float vd = FLT_MAX; int vn = 0x7fffffff;
    if (lane < NSEG * KK) {
        vd = cand_d[pair * NSEG * KK + lane];
        vn = cand_n[pair * NSEG * KK + lane];
    }

    int myn = 0;
    for (int r = 0; r < KK; ++r) {
        float bv = vd; int bn = vn;
        for (int s = 1; s < 64; s <<= 1) {
            float ov = __shfl_xor(bv, s);
            int   on = __shfl_xor(bn, s);
            bool cc = (ov < bv) || (ov == bv && on < bn);
            bv = cc ? ov : bv;
            bn = cc ? on : bn;
        }
        if (vn == bn) vd = FLT_MAX;   // n unique across lanes
        if (lane == r) myn = bn;
        if (lane == 0) sel[pair * KK + r] = bn;
    }
    myn = myn < 0 ? 0 : (myn >= NN ? NN - 1 : myn);  // fault guard

    float l1 = 0.0f, gio = 0.0f;
    if (lane < KK) {
        float4 p = ((const float4*)pred_boxes)[b * NN + myn];
        l1 = fabsf(p.x - gt.x) + fabsf(p.y - gt.y) + fabsf(p.z - gt.z) + fabsf(p.w - gt.w);

        float ax1 = p.x - 0.5f * p.z, ay1 = p.y - 0.5f * p.w;
        float ax2 = p.x + 0.5f * p.z, ay2 = p.y + 0.5f * p.w;
        float bx1 = gt.x - 0.5f * gt.z, by1 = gt.y - 0.5f * gt.w;
        float bx2 = gt.x + 0.5f * gt.z, by2 = gt.y + 0.5f * gt.w;

        float area_a = (ax2 - ax1) * (ay2 - ay1);
        float area_b = (bx2 - bx1) * (by2 - by1);
        float ix1 = fmaxf(ax1, bx1), iy1 = fmaxf(ay1, by1);
        float ix2 = fminf(ax2, bx2), iy2 = fminf(ay2, by2);
        float iw = fmaxf(ix2 - ix1, 0.0f), ih = fmaxf(iy2 - iy1, 0.0f);
        float inter = iw * ih;
        float uni = area_a + area_b - inter;
        float iou = inter / uni;
        float ccx1 = fminf(ax1, bx1), ccy1 = fminf(ay1, by1);
        float ccx2 = fmaxf(ax2, bx2), ccy2 = fmaxf(ay2, by2);
        float cw = fmaxf(ccx2 - ccx1, 0.0f), ch = fmaxf(ccy2 - ccy1, 0.0f);
        float ac = cw * ch;
        float giou = iou - (ac - uni) / ac;
        gio = 1.0f - giou;
    }
    for (int o = 32; o > 0; o >>= 1) {
        l1 += __shfl_down(l1, o);
        gio += __shfl_down(gio, o);
    }
    if (lane == 0) {
        atomicAdd(&acc[1], (double)l1);
        atomicAdd(&acc[2], (double)gio);
    }
}

// Kernel B: main focal sum over all B*N*C logits (t=0 formula everywhere)
__global__ __launch_bounds__(256) void focal_main_kernel(
    const float* __restrict__ logits, double* __restrict__ acc, int nvec4)
{
    const float4* v = (const float4*)logits;
    float s0 = 0.f, s1 = 0.f, s2 = 0.f, s3 = 0.f;
    int stride = gridDim.x * blockDim.x;
    for (int i = blockIdx.x * blockDim.x + threadIdx.x; i < nvec4; i += stride) {
        float4 x = v[i];
        s0 += focal_t0(x.x);
        s1 += focal_t0(x.y);
        s2 += focal_t0(x.z);
        s3 += focal_t0(x.w);
    }
    double d = (double)((s0 + s1) + (s2 + s3));
#pragma unroll
    for (int o = 32; o > 0; o >>= 1) d += __shfl_down(d, o);
    __shared__ double wsum[4];
    if ((threadIdx.x & 63) == 0) wsum[threadIdx.x >> 6] = d;
    __syncthreads();
    if (threadIdx.x == 0) {
        atomicAdd(&acc[0], wsum[0] + wsum[1] + wsum[2] + wsum[3]);
    }
}

// Kernel C (v3): 4 blocks per image. Dedup via batched, explicitly-bitwise
// scan: 8 independent LDS reads per group (pipelined, no short-circuit
// branches, no loop-carried lgkmcnt(0) chain).
#define EPB 144   // elements per block (576 / 4)
__global__ __launch_bounds__(256) void correction_kernel(
    const float* __restrict__ logits, const int* __restrict__ sel,
    const int* __restrict__ gt_labels, double* __restrict__ acc)
{
    int bq = blockIdx.x;           // 0..63
    int b  = bq >> 2;              // image
    int q  = bq & 3;               // quarter

    __shared__ int keys[GG * KK];
    for (int e = threadIdx.x; e < GG * KK; e += blockDim.x) {
        int g = e / KK;
        int n = sel[(b * GG + g) * KK + (e - g * KK)];
        keys[e] = n * CC + gt_labels[b * GG + g];
    }
    __syncthreads();

    bool active = (threadIdx.x < EPB);
    int e = q * EPB + (active ? threadIdx.x : 0);   // bounded index
    int k = keys[e];
    k = active ? k : -1;                            // -1 never matches

    // branch-free duplicate test, 8 pipelined LDS reads per group
    int dup = 0;
    for (int e2 = 0; e2 < GG * KK; e2 += 8) {
        int k0 = keys[e2 + 0];
        int k1 = keys[e2 + 1];
        int k2 = keys[e2 + 2];
        int k3 = keys[e2 + 3];
        int k4 = keys[e2 + 4];
        int k5 = keys[e2 + 5];
        int k6 = keys[e2 + 6];
        int k7 = keys[e2 + 7];
        int h = 0;
        h |= (int)(k0 == k) & (int)(e2 + 0 < e);
        h |= (int)(k1 == k) & (int)(e2 + 1 < e);
        h |= (int)(k2 == k) & (int)(e2 + 2 < e);
        h |= (int)(k3 == k) & (int)(e2 + 3 < e);
        h |= (int)(k4 == k) & (int)(e2 + 4 < e);
        h |= (int)(k5 == k) & (int)(e2 + 5 < e);
        h |= (int)(k6 == k) & (int)(e2 + 6 < e);
        h |= (int)(k7 == k) & (int)(e2 + 7 < e);
        dup |= h;
    }

    float corr = 0.0f;
    if (active && dup == 0) {
        corr = focal_corr(logits[(long long)b * NN * CC + k]);
    }

    double d = (double)corr;
#pragma unroll
    for (int o = 32; o > 0; o >>= 1) d += __shfl_down(d, o);
    __shared__ double wsum[4];
    if ((threadIdx.x & 63) == 0) wsum[threadIdx.x >> 6] = d;
    __syncthreads();
    if (threadIdx.x == 0) {
        atomicAdd(&acc[0], wsum[0] + wsum[1] + wsum[2] + wsum[3]);
    }
}

// Kernel D: finalize means
__global__ void finalize_kernel(const double* __restrict__ acc, float* __restrict__ out)
{
    if (threadIdx.x == 0 && blockIdx.x == 0) {
        out[0] = (float)(acc[0] / (double)((long long)BB * NN * CC));
        out[1] = (float)(acc[1] / (double)(BB * GG * KK * 4));
        out[2] = (float)(acc[2] / (double)(BB * GG * KK));
    }
}

extern "C" void kernel_launch(void* const* d_in, const int* in_sizes, int n_in,
                              void* d_out, int out_size, void* d_ws, size_t ws_size,
                              hipStream_t stream) {
    const float* pred_logits = (const float*)d_in[0];  // (B,N,C)
    const float* pred_boxes  = (const float*)d_in[1];  // (B,N,4)
    const float* locations   = (const float*)d_in[2];  // (N,2)
    const float* gt_boxes    = (const float*)d_in[3];  // (B,G,4)
    const int*   gt_labels   = (const int*)d_in[4];    // (B,G)
    float* out = (float*)d_out;

    // workspace layout
    double* acc   = (double*)d_ws;                         // 3 doubles
    int*    sel   = (int*)((char*)d_ws + 64);              // 1024*9 ints  = 36864 B
    float*  candd = (float*)((char*)d_ws + 64 + 36864);    // 4096*9 floats = 147456 B
    int*    candn = (int*)((char*)d_ws + 64 + 36864 + 147456);

    hipMemsetAsync(d_ws, 0, 64, stream);

    // A1: per-segment top-9 (1024 blocks x 4 waves = 4096 wave-segments)
    topk_seg_kernel<<<BB * GG, 256, 0, stream>>>(locations, gt_boxes, candd, candn);

    // A2: merge 36 candidates/pair + bbox epilogue (256 blocks x 4 waves)
    topk_merge_kernel<<<BB * GG / 4, 256, 0, stream>>>(pred_boxes, gt_boxes, candd, candn, acc, sel);

    // B: focal main sum
    int nvec4 = (BB * NN * CC) / 4;
    focal_main_kernel<<<2048, 256, 0, stream>>>(pred_logits, acc, nvec4);

    // C: corrections (4 blocks per image)
    correction_kernel<<<BB * 4, 256, 0, stream>>>(pred_logits, sel, gt_labels, acc);

    // D: finalize
    finalize_kernel<<<1, 64, 0, stream>>>(acc, out);
}